// Round 18
// baseline (1260.799 us; speedup 1.0000x reference)
//
#include <hip/hip_runtime.h>
#include <hip/hip_bf16.h>

#define N_NEUR 2000
#define N_E    1600
#define KPAD   2048
#define NCOND  96
#define NSTEP  60
#define NAVG   15
#define NBLK   126                     // 63 tiles x 32 neurons x 2 halves
#define NTILE  63
#define RSTEP  (NCOND * KPAD)          // elems per r step-buffer (196608)

#define DEGF   0.017453292519943295f
#define TWO_DEG 0.03490658503988659f

typedef __attribute__((ext_vector_type(8))) short bf16x8;
typedef __attribute__((ext_vector_type(4))) float f32x4;

// ---------------- Ricciardi transfer function (fast transcendentals) ----------------
__device__ __forceinline__ float f_ricci(float x){
    float t = -x / (1.0f + x);
    float p = 0.14805913578876898f;
    p = fmaf(p, t, 0.64290613877355551f);
    p = fmaf(p, t, 1.0616084849547165f);
    p = fmaf(p, t, 0.93524391761244940f);
    p = fmaf(p, t, 0.62718906618071668f);
    p = fmaf(p, t, 0.32171431660633076f);
    p = fmaf(p, t, 0.32056016125642045f);
    p = fmaf(p, t, 0.77373949685442023f);
    p = fmaf(p, t, 0.22757881388024176f);
    return __logf(2.0f * x + 1.0f) + p * t;
}

__device__ __forceinline__ float g_ricci(float x){
    float z = x / (2.0f + x);
    float z2 = z * z, z3 = z2 * z, z4 = z2 * z2, z5 = z4 * z, z6 = z3 * z3, z7 = z6 * z, z8 = z4 * z4;
    float en = 3.5441754117462949f * z - 7.0529131065835378f * z2 - 56.532378057580381f * z3
             + 279.56761105465944f * z4 - 520.37554793489681f * z5
             + 456.58245777026514f * z6 - 155.73340457809226f * z7;
    float de = 1.0f - 4.1357968834226053f * z - 7.2984226138266743f * z2
             + 98.656602235468327f * z3 - 334.20436223415163f * z4
             + 601.08633903294185f * z5 - 599.58577549598340f * z6
             + 277.18420330693891f * z7 - 16.445022798669722f * z8;
    return en / de;
}

__device__ __forceinline__ float phi_rate(float mu, float sigma, float tau_ref){
    const float tau = 0.01f;
    float xp = mu / sigma;
    float xm = (mu - 20.0f) / sigma;
    float r;
    if (xm > 0.0f){
        r = 1.0f / (f_ricci(xp) - f_ricci(xm));
    } else if (xp > 0.0f){
        float nxm = fminf(-xm, 9.0f);
        r = 1.0f / (f_ricci(xp) + __expf(nxm * nxm) * g_ricci(nxm));
    } else {
        float nxp = fminf(fmaxf(-xp, 0.0f), 9.0f);
        float nxm = fminf(-xm, 9.0f);
        float arg = g_ricci(nxm) - __expf(nxp * nxp - nxm * nxm) * g_ricci(nxp);
        r = __expf(-nxm * nxm - __logf(fmaxf(arg, 1e-12f)));
    }
    return 1.0f / (tau_ref + tau / fmaxf(r, 1e-12f));
}

__device__ __forceinline__ float pref_of(int n){
    return (n < N_E) ? (float)n * (179.99f / 1599.0f)
                     : (float)(n - N_E) * (179.99f / 399.0f);
}

__device__ __forceinline__ unsigned short bf16_rne(float f){
    unsigned int u = __float_as_uint(f);
    u = (u + 0x7fffu + ((u >> 16) & 1u)) >> 16;
    return (unsigned short)u;
}

__device__ __forceinline__ void vmdrain(){
    asm volatile("s_waitcnt vmcnt(0)" ::: "memory");
}

// ---------------- weight build: Wh, Wl (split), W2h, padded to 2048x2048 ----------------
__global__ __launch_bounds__(256) void build_w_kernel(
    const float* __restrict__ jp, const float* __restrict__ pp,
    const float* __restrict__ wp, const float* __restrict__ rnd,
    unsigned short* __restrict__ Wh, unsigned short* __restrict__ Wl,
    unsigned short* __restrict__ W2h)
{
    int e = blockIdx.x * 256 + threadIdx.x;     // over 2048*2048
    int i = e >> 11;
    int j = e & (KPAD - 1);
    float w = 0.0f;
    if (i < N_NEUR && j < N_NEUR){
        int isIi = (i >= N_E) ? 1 : 0;
        int isIj = (j >= N_E) ? 1 : 0;
        int conn = 2 * isIj + isIi;
        float J  = expf(jp[conn]);
        float P  = 1.0f / (1.0f + expf(-2.0f * expf(pp[conn])));
        float Wd = expf(wp[conn]);
        float diff = fabsf(pref_of(i) - pref_of(j));
        float dw = DEGF * Wd;
        float z = expf((cosf(TWO_DEG * diff) - 1.0f) / (4.0f * dw * dw));
        float s = 1.0f / (1.0f + expf(-32.0f * (P * z - rnd[i * N_NEUR + j])));
        float sign = isIj ? -1.0f : 1.0f;
        w = sign * J * s;
    }
    unsigned short hb = bf16_rne(w);
    float hf = __uint_as_float(((unsigned int)hb) << 16);
    Wh[e] = hb;
    Wl[e] = bf16_rne(w - hf);
    W2h[e] = bf16_rne(w * w);
}

__global__ __launch_bounds__(256) void build_im_kernel(float* __restrict__ IM)
{
    int e = blockIdx.x * 256 + threadIdx.x;     // over 96*2048
    int c = e >> 11;
    int n = e & (KPAD - 1);
    if (n >= N_NEUR){ IM[e] = 0.0f; return; }
    const float contrasts[8] = {0.0f, 0.0432773f, 0.103411f, 0.186966f,
                                0.303066f, 0.464386f, 0.68854f, 1.0f};
    int ci = c / 12;
    int oi = c - ci * 12;
    float orient = (float)oi * 15.0f;
    const float dw = DEGF * 30.0f;
    float g = expf((cosf(TWO_DEG * (orient - pref_of(n))) - 1.0f) / (4.0f * dw * dw));
    IM[e] = contrasts[ci] * 20.0f * g;
}

// ---------------- persistent async-dataflow solver, M=32 neurons/block ----------------
// grid 126 x 512 (8 waves), 1 block/CU. Block = (tile = bid>>1 -> neurons
// [tile*32,+32), half = bid&1 -> conds [half*48,+48)). Halved block count
// halves the per-step first-touch A traffic (R17 diagnosis: concurrent L2-cold
// A reads dominate the step); doubled per-block MFMA improves latency overlap.
// Dataflow sync (R11-proven): fresh buffer per step, agent stores -> vmcnt
// drain -> per-(tile,half) flag; consumer waves poll their 8 producer flags
// (agent loads) then read A with normal cached loads (write-once buffers;
// kernel boundary invalidates across replays). Two-phase 8->4 LDS reduction
// (R14-validated). Depth-3 A ring.
// mu  <- rh*Wh + rh*Wl + rl*Wh ; sg2 <- rh*W2h + rl*W2h   (split-bf16 ~ fp32)
__global__ __launch_bounds__(512, 2) void solve_kernel(
    const unsigned short* __restrict__ Wh, const unsigned short* __restrict__ Wl,
    const unsigned short* __restrict__ W2h,
    unsigned short* __restrict__ rh, unsigned short* __restrict__ rl,
    unsigned int* __restrict__ flags,
    const float* __restrict__ IM, float* __restrict__ out,
    float* __restrict__ mloc)
{
    __shared__ float red[4][64][49];    // 50176 B (two-phase partials)
    __shared__ float vbuf[48][32];      //  6144 B

    const int bid  = blockIdx.x;        // 0..125
    const int tile = bid >> 1;          // 0..62
    const int half = bid & 1;
    const int t  = threadIdx.x;
    const int wv = t >> 6;
    const int ln = t & 63;
    const int nbase = tile * 32;
    const int cbase = half * 48;

    const int lrow = ln & 15;
    const int lk8  = (ln >> 4) * 8;
    const int kw   = wv * 256 + lk8;

    // ---- W fragment pointers (two neuron-groups); compiler reloads from L2 ----
    const int wrow0 = (nbase + lrow) * KPAD + kw;
    const int wrow1 = (nbase + 16 + lrow) * KPAD + kw;
    bf16x8 wh_f[8][2], wl_f[8][2], w2_f[8][2];
    #pragma unroll
    for (int s = 0; s < 8; ++s){
        wh_f[s][0] = *reinterpret_cast<const bf16x8*>(Wh  + wrow0 + s * 32);
        wh_f[s][1] = *reinterpret_cast<const bf16x8*>(Wh  + wrow1 + s * 32);
        wl_f[s][0] = *reinterpret_cast<const bf16x8*>(Wl  + wrow0 + s * 32);
        wl_f[s][1] = *reinterpret_cast<const bf16x8*>(Wl  + wrow1 + s * 32);
        w2_f[s][0] = *reinterpret_cast<const bf16x8*>(W2h + wrow0 + s * 32);
        w2_f[s][1] = *reinterpret_cast<const bf16x8*>(W2h + wrow1 + s * 32);
    }

    // flag-poll: lane ln<8 watches tile wv*8+ln (tile 63 = pure pad, no flag;
    // its K-columns are >=2016 where W==0, so stale A-values are annihilated)
    const int wt = wv * 8 + (ln & 7);
    const bool need = (ln < 8) && (wt < NTILE);
    const unsigned int* fpoll = &flags[((size_t)wt * 2 + half) * 16];

    // ---- epilogue precompute: thread t owns outputs o = t, t+512, t+1024 ----
    int   ep_idx[3], ep_lane[3], ep_r[3], ep_o[3];
    float ep_im[3], ep_tref[3], ep_gain[3];
    bool  ep_real[3];
    float rfv[3] = {0.0f, 0.0f, 0.0f};
    #pragma unroll
    for (int u = 0; u < 3; ++u){
        const int o = t + u * 512;      // 0..1535
        const int c_l = o >> 5, n_l = o & 31;
        const int m_e = c_l >> 4;
        const int rr  = c_l & 15;
        const int ng  = n_l >> 4;
        ep_idx[u]  = (m_e * 2 + ng) * 4 + (rr & 3);
        ep_lane[u] = (rr >> 2) * 16 + (n_l & 15);
        const int c_g = cbase + c_l;
        const int i_g = nbase + n_l;
        ep_real[u] = (i_g < N_NEUR);
        ep_r[u]    = c_g * KPAD + i_g;
        ep_o[u]    = i_g * NCOND + c_g;
        ep_im[u]   = ep_real[u] ? IM[c_g * KPAD + i_g] : 0.0f;
        const bool isI = (i_g >= N_E);
        ep_tref[u] = isI ? 0.001f : 0.005f;
        ep_gain[u] = isI ? 0.2f : 0.1f;
    }

    const int ro0 = (cbase + lrow) * KPAD + kw;     // A base (elems) within a buffer

    for (int st = 0; st < NSTEP; ++st){
        // -------- wait for the 8 producers covering this wave's K-slice --------
        if (st > 0){
            const unsigned int* fp = fpoll + (size_t)st * 256 * 16;
            for (;;){
                unsigned int vfl = need ? __hip_atomic_load(fp, __ATOMIC_RELAXED,
                                                            __HIP_MEMORY_SCOPE_AGENT) : 1u;
                if (__all(vfl != 0)) break;
            }
        }

        // -------- depth-3 pipelined A loads (normal cached) + MFMA --------
        const unsigned short* bhp = rh + (size_t)st * RSTEP + ro0;
        const unsigned short* blp = rl + (size_t)st * RSTEP + ro0;

        f32x4 accm[3][2], accs[3][2];
        #pragma unroll
        for (int m = 0; m < 3; ++m)
            #pragma unroll
            for (int n = 0; n < 2; ++n){
                accm[m][n] = (f32x4){0.0f, 0.0f, 0.0f, 0.0f};
                accs[m][n] = (f32x4){0.0f, 0.0f, 0.0f, 0.0f};
            }

        bf16x8 fh[3][3], fl[3][3];
        #define LOADF(b, s) do {                                                        \
            fh[b][0] = *reinterpret_cast<const bf16x8*>(bhp + (s) * 32            );    \
            fh[b][1] = *reinterpret_cast<const bf16x8*>(bhp + (s) * 32 + 16 * KPAD);    \
            fh[b][2] = *reinterpret_cast<const bf16x8*>(bhp + (s) * 32 + 32 * KPAD);    \
            fl[b][0] = *reinterpret_cast<const bf16x8*>(blp + (s) * 32            );    \
            fl[b][1] = *reinterpret_cast<const bf16x8*>(blp + (s) * 32 + 16 * KPAD);    \
            fl[b][2] = *reinterpret_cast<const bf16x8*>(blp + (s) * 32 + 32 * KPAD);    \
        } while (0)

        LOADF(0, 0);
        LOADF(1, 1);
        #pragma unroll
        for (int s = 0; s < 8; ++s){
            const int cur = s % 3;
            if (s + 2 < 8){ const int nx = (s + 2) % 3; LOADF(nx, s + 2); }
            #pragma unroll
            for (int m = 0; m < 3; ++m)
                #pragma unroll
                for (int n = 0; n < 2; ++n){
                    accm[m][n] = __builtin_amdgcn_mfma_f32_16x16x32_bf16(fh[cur][m], wh_f[s][n], accm[m][n], 0, 0, 0);
                    accm[m][n] = __builtin_amdgcn_mfma_f32_16x16x32_bf16(fh[cur][m], wl_f[s][n], accm[m][n], 0, 0, 0);
                    accm[m][n] = __builtin_amdgcn_mfma_f32_16x16x32_bf16(fl[cur][m], wh_f[s][n], accm[m][n], 0, 0, 0);
                    accs[m][n] = __builtin_amdgcn_mfma_f32_16x16x32_bf16(fh[cur][m], w2_f[s][n], accs[m][n], 0, 0, 0);
                    accs[m][n] = __builtin_amdgcn_mfma_f32_16x16x32_bf16(fl[cur][m], w2_f[s][n], accs[m][n], 0, 0, 0);
                }
        }
        #undef LOADF

        // -------- two-phase cross-wave K-reduction (8 -> 4 -> epilogue) --------
        if (wv >= 4){
            #pragma unroll
            for (int m = 0; m < 3; ++m)
                #pragma unroll
                for (int n = 0; n < 2; ++n)
                    #pragma unroll
                    for (int q = 0; q < 4; ++q){
                        red[wv - 4][ln][(m * 2 + n) * 4 + q]      = accm[m][n][q];
                        red[wv - 4][ln][24 + (m * 2 + n) * 4 + q] = accs[m][n][q];
                    }
        }
        __syncthreads();
        if (wv < 4){
            #pragma unroll
            for (int m = 0; m < 3; ++m)
                #pragma unroll
                for (int n = 0; n < 2; ++n)
                    #pragma unroll
                    for (int q = 0; q < 4; ++q){
                        red[wv][ln][(m * 2 + n) * 4 + q]      += accm[m][n][q];
                        red[wv][ln][24 + (m * 2 + n) * 4 + q] += accs[m][n][q];
                    }
        }
        __syncthreads();

        unsigned short* rho = rh + (size_t)(st + 1) * RSTEP;
        unsigned short* rlo = rl + (size_t)(st + 1) * RSTEP;
        const bool track = (st >= NSTEP - NAVG);

        // -------- epilogue: Phi + update + agent r stores (3 outputs/thread) ----
        #pragma unroll
        for (int u = 0; u < 3; ++u){
            float ms = 0.0f, ss = 0.0f;
            #pragma unroll
            for (int w = 0; w < 4; ++w){
                ms += red[w][ep_lane[u]][ep_idx[u]];
                ss += red[w][ep_lane[u]][24 + ep_idx[u]];
            }
            const float mu = fmaf(0.01f, ms, ep_im[u]);
            const float sg = sqrtf(fmaf(0.01f, ss, 25.0f));
            const float rate = phi_rate(mu, sg, ep_tref[u]);
            const float dr = ep_gain[u] * (rate - rfv[u]);
            const float rnew = rfv[u] + dr;
            rfv[u] = rnew;
            if (ep_real[u]){
                const unsigned short hb = bf16_rne(rnew);
                const float hf = __uint_as_float(((unsigned int)hb) << 16);
                __hip_atomic_store(&rho[ep_r[u]], hb,
                                   __ATOMIC_RELAXED, __HIP_MEMORY_SCOPE_AGENT);
                __hip_atomic_store(&rlo[ep_r[u]], bf16_rne(rnew - hf),
                                   __ATOMIC_RELAXED, __HIP_MEMORY_SCOPE_AGENT);
                if (st == NSTEP - 1) out[ep_o[u]] = rnew;
            }
            if (track){
                const int o = t + u * 512;
                vbuf[o >> 5][o & 31] = ep_real[u] ? (fabsf(dr) / fmaxf(fabsf(rnew), 1.0f)) : 0.0f;
            }
        }

        // -------- publish: drain r stores, then set flag --------
        vmdrain();
        __syncthreads();        // all waves' stores drained; red[] safe to reuse
        if (st < NSTEP - 1 && t == 0)
            __hip_atomic_store(&flags[((size_t)(st + 1) * 256 + tile * 2 + half) * 16], 1u,
                               __ATOMIC_RELAXED, __HIP_MEMORY_SCOPE_AGENT);
        if (track && t < 48){
            float mx = 0.0f;
            #pragma unroll
            for (int j = 0; j < 32; ++j) mx = fmaxf(mx, vbuf[t][j]);
            mloc[((size_t)(st - (NSTEP - NAVG)) * NBLK + bid) * 48 + t] = mx;
        }
    }
}

// ---------------- finalize A: cross-block max per (step, cond) ----------------
__global__ __launch_bounds__(128) void finalize_max_kernel(
    const float* __restrict__ mloc, float* __restrict__ m2)
{
    int idx = blockIdx.x * 128 + threadIdx.x;   // over 15*96 = 1440
    if (idx >= NAVG * NCOND) return;
    int st = idx / NCOND, c = idx - st * NCOND;
    int half = c / 48, cl = c - half * 48;
    float mx = 0.0f;
    for (int tile = 0; tile < NTILE; ++tile)
        mx = fmaxf(mx, mloc[((size_t)st * NBLK + tile * 2 + half) * 48 + cl]);
    m2[idx] = mx;
}

// ---------------- finalize B: mean over 15x96, scale by 1/XTOL ----------------
__global__ __launch_bounds__(256) void finalize_sum_kernel(
    const float* __restrict__ m2, float* __restrict__ out)
{
    __shared__ float sbuf[256];
    float s = 0.0f;
    for (int i = threadIdx.x; i < NAVG * NCOND; i += 256) s += m2[i];
    sbuf[threadIdx.x] = s;
    __syncthreads();
    for (int st = 128; st > 0; st >>= 1){
        if (threadIdx.x < st) sbuf[threadIdx.x] += sbuf[threadIdx.x + st];
        __syncthreads();
    }
    if (threadIdx.x == 0)
        out[N_NEUR * NCOND] = sbuf[0] / (float)(NAVG * NCOND) * 1e5f;
}

extern "C" void kernel_launch(void* const* d_in, const int* in_sizes, int n_in,
                              void* d_out, int out_size, void* d_ws, size_t ws_size,
                              hipStream_t stream) {
    const float* jp  = (const float*)d_in[0];
    const float* pp  = (const float*)d_in[1];
    const float* wp  = (const float*)d_in[2];
    const float* rnd = (const float*)d_in[3];
    float* out = (float*)d_out;

    const size_t WELEMS = (size_t)KPAD * KPAD;          // 4,194,304
    const size_t RBUFS  = (size_t)(NSTEP + 1) * RSTEP;  // 61 step-buffers
    unsigned short* Wh  = (unsigned short*)d_ws;
    unsigned short* Wl  = Wh  + WELEMS;
    unsigned short* W2h = Wl  + WELEMS;
    float* IM   = (float*)(W2h + WELEMS);               // 96*2048
    float* mloc = IM + (size_t)NCOND * KPAD;            // 15*126*48 (fully rewritten)
    float* m2   = mloc + (size_t)NAVG * NBLK * 48;      // 1440 (fully rewritten)
    unsigned short* rh = (unsigned short*)(m2 + NAVG * NCOND);
    unsigned short* rl = rh + RBUFS;
    unsigned int* flags = (unsigned int*)(rl + RBUFS);  // 61*256*16 uints

    // zero: step-0 r buffers (r0 = 0, incl. pads) and all flags
    hipMemsetAsync(rh, 0, (size_t)RSTEP * sizeof(unsigned short), stream);
    hipMemsetAsync(rl, 0, (size_t)RSTEP * sizeof(unsigned short), stream);
    hipMemsetAsync(flags, 0, (size_t)(NSTEP + 1) * 256 * 16 * sizeof(unsigned int), stream);

    build_w_kernel<<<(int)(WELEMS / 256), 256, 0, stream>>>(jp, pp, wp, rnd, Wh, Wl, W2h);
    build_im_kernel<<<(int)((NCOND * KPAD) / 256), 256, 0, stream>>>(IM);

    // plain launch: 126 blocks <= 256 CUs, 1 block/CU, no grid-wide sync needed
    solve_kernel<<<dim3(NBLK), dim3(512), 0, stream>>>(
        Wh, Wl, W2h, rh, rl, flags, IM, out, mloc);

    finalize_max_kernel<<<(NAVG * NCOND + 127) / 128, 128, 0, stream>>>(mloc, m2);
    finalize_sum_kernel<<<1, 256, 0, stream>>>(m2, out);
}

// Round 19
// 869.324 us; speedup vs baseline: 1.4503x; 1.4503x over previous
//
#include <hip/hip_runtime.h>
#include <hip/hip_bf16.h>

#define N_NEUR 2000
#define N_E    1600
#define KPAD   2048
#define NCOND  96
#define NSTEP  60
#define NAVG   15
#define NBLK   250
#define RSTEP  (NCOND * KPAD)          // elems per r step-buffer (196608)

#define DEGF   0.017453292519943295f
#define TWO_DEG 0.03490658503988659f

typedef __attribute__((ext_vector_type(8))) short bf16x8;
typedef __attribute__((ext_vector_type(4))) float f32x4;

// ---------------- Ricciardi transfer function (fast transcendentals) ----------------
__device__ __forceinline__ float f_ricci(float x){
    float t = -x / (1.0f + x);
    float p = 0.14805913578876898f;
    p = fmaf(p, t, 0.64290613877355551f);
    p = fmaf(p, t, 1.0616084849547165f);
    p = fmaf(p, t, 0.93524391761244940f);
    p = fmaf(p, t, 0.62718906618071668f);
    p = fmaf(p, t, 0.32171431660633076f);
    p = fmaf(p, t, 0.32056016125642045f);
    p = fmaf(p, t, 0.77373949685442023f);
    p = fmaf(p, t, 0.22757881388024176f);
    return __logf(2.0f * x + 1.0f) + p * t;
}

__device__ __forceinline__ float g_ricci(float x){
    float z = x / (2.0f + x);
    float z2 = z * z, z3 = z2 * z, z4 = z2 * z2, z5 = z4 * z, z6 = z3 * z3, z7 = z6 * z, z8 = z4 * z4;
    float en = 3.5441754117462949f * z - 7.0529131065835378f * z2 - 56.532378057580381f * z3
             + 279.56761105465944f * z4 - 520.37554793489681f * z5
             + 456.58245777026514f * z6 - 155.73340457809226f * z7;
    float de = 1.0f - 4.1357968834226053f * z - 7.2984226138266743f * z2
             + 98.656602235468327f * z3 - 334.20436223415163f * z4
             + 601.08633903294185f * z5 - 599.58577549598340f * z6
             + 277.18420330693891f * z7 - 16.445022798669722f * z8;
    return en / de;
}

__device__ __forceinline__ float phi_rate(float mu, float sigma, float tau_ref){
    const float tau = 0.01f;
    float xp = mu / sigma;
    float xm = (mu - 20.0f) / sigma;
    float r;
    if (xm > 0.0f){
        r = 1.0f / (f_ricci(xp) - f_ricci(xm));
    } else if (xp > 0.0f){
        float nxm = fminf(-xm, 9.0f);
        r = 1.0f / (f_ricci(xp) + __expf(nxm * nxm) * g_ricci(nxm));
    } else {
        float nxp = fminf(fmaxf(-xp, 0.0f), 9.0f);
        float nxm = fminf(-xm, 9.0f);
        float arg = g_ricci(nxm) - __expf(nxp * nxp - nxm * nxm) * g_ricci(nxp);
        r = __expf(-nxm * nxm - __logf(fmaxf(arg, 1e-12f)));
    }
    return 1.0f / (tau_ref + tau / fmaxf(r, 1e-12f));
}

__device__ __forceinline__ float pref_of(int n){
    return (n < N_E) ? (float)n * (179.99f / 1599.0f)
                     : (float)(n - N_E) * (179.99f / 399.0f);
}

__device__ __forceinline__ unsigned short bf16_rne(float f){
    unsigned int u = __float_as_uint(f);
    u = (u + 0x7fffu + ((u >> 16) & 1u)) >> 16;
    return (unsigned short)u;
}

__device__ __forceinline__ void vmdrain(){
    asm volatile("s_waitcnt vmcnt(0)" ::: "memory");
}

// ---------------- weight build: Wh, Wl (split), W2h, padded to 2048x2048 ----------------
__global__ __launch_bounds__(256) void build_w_kernel(
    const float* __restrict__ jp, const float* __restrict__ pp,
    const float* __restrict__ wp, const float* __restrict__ rnd,
    unsigned short* __restrict__ Wh, unsigned short* __restrict__ Wl,
    unsigned short* __restrict__ W2h)
{
    int e = blockIdx.x * 256 + threadIdx.x;     // over 2048*2048
    int i = e >> 11;
    int j = e & (KPAD - 1);
    float w = 0.0f;
    if (i < N_NEUR && j < N_NEUR){
        int isIi = (i >= N_E) ? 1 : 0;
        int isIj = (j >= N_E) ? 1 : 0;
        int conn = 2 * isIj + isIi;
        float J  = expf(jp[conn]);
        float P  = 1.0f / (1.0f + expf(-2.0f * expf(pp[conn])));
        float Wd = expf(wp[conn]);
        float diff = fabsf(pref_of(i) - pref_of(j));
        float dw = DEGF * Wd;
        float z = expf((cosf(TWO_DEG * diff) - 1.0f) / (4.0f * dw * dw));
        float s = 1.0f / (1.0f + expf(-32.0f * (P * z - rnd[i * N_NEUR + j])));
        float sign = isIj ? -1.0f : 1.0f;
        w = sign * J * s;
    }
    unsigned short hb = bf16_rne(w);
    float hf = __uint_as_float(((unsigned int)hb) << 16);
    Wh[e] = hb;
    Wl[e] = bf16_rne(w - hf);
    W2h[e] = bf16_rne(w * w);
}

__global__ __launch_bounds__(256) void build_im_kernel(float* __restrict__ IM)
{
    int e = blockIdx.x * 256 + threadIdx.x;     // over 96*2048
    int c = e >> 11;
    int n = e & (KPAD - 1);
    if (n >= N_NEUR){ IM[e] = 0.0f; return; }
    const float contrasts[8] = {0.0f, 0.0432773f, 0.103411f, 0.186966f,
                                0.303066f, 0.464386f, 0.68854f, 1.0f};
    int ci = c / 12;
    int oi = c - ci * 12;
    float orient = (float)oi * 15.0f;
    const float dw = DEGF * 30.0f;
    float g = expf((cosf(TWO_DEG * (orient - pref_of(n))) - 1.0f) / (4.0f * dw * dw));
    IM[e] = contrasts[ci] * 20.0f * g;
}

// ---------------- persistent async-dataflow solver (R15 + progressive K-poll) --------
// grid 250 x 512 (8 waves), 1 block/CU. Fresh r buffer per step; producers
// agent-store their slice, vmcnt-drain, set flag[st+1][tile][half]. Consumers
// poll at K-PAIR granularity inside the K-loop: before loading k-step s's
// fragments (tiles 2s, 2s+1 of the wave's slice), 2 lanes poll just those 2
// flags. Compute starts as soon as the first producers are ready; the
// straggler tail hides under MFMA of ready segments. A reads are normal
// cached loads (write-once buffers; kernel boundary invalidates across
// replays). Depth-3 A ring.
// mu  <- rh*Wh + rh*Wl + rl*Wh ; sg2 <- rh*W2h + rl*W2h   (split-bf16 ~ fp32)
__global__ __launch_bounds__(512, 2) void solve_kernel(
    const unsigned short* __restrict__ Wh, const unsigned short* __restrict__ Wl,
    const unsigned short* __restrict__ W2h,
    unsigned short* __restrict__ rh, unsigned short* __restrict__ rl,
    unsigned int* __restrict__ flags,
    const float* __restrict__ IM, float* __restrict__ out,
    float* __restrict__ mloc)
{
    __shared__ float red[8][64][25];
    __shared__ float vbuf[48][16];

    const int bid  = blockIdx.x;        // 0..249
    const int tile = bid >> 1;          // 0..124
    const int half = bid & 1;
    const int t  = threadIdx.x;
    const int wv = t >> 6;
    const int ln = t & 63;
    const int nbase = tile * 16;
    const int cbase = half * 48;

    const int lrow = ln & 15;
    const int lk8  = (ln >> 4) * 8;
    const int kw   = wv * 256 + lk8;
    const int nrow = nbase + lrow;

    // ---- preload W fragments (reloaded per step by regalloc; L2-resident) ----
    const unsigned short* pwh = &Wh [nrow * KPAD + kw];
    const unsigned short* pwl = &Wl [nrow * KPAD + kw];
    const unsigned short* pw2 = &W2h[nrow * KPAD + kw];
    bf16x8 wh_f[8], wl_f[8], w2_f[8];
    #pragma unroll
    for (int s = 0; s < 8; ++s){
        wh_f[s] = *reinterpret_cast<const bf16x8*>(pwh + s * 32);
        wl_f[s] = *reinterpret_cast<const bf16x8*>(pwl + s * 32);
        w2_f[s] = *reinterpret_cast<const bf16x8*>(pw2 + s * 32);
    }

    // progressive poll: for k-step s, lanes 0..1 watch tiles wv*16+2s+ln
    // (tiles >=125 don't exist; their K-columns hit W==0, values annihilated)

    // ---- epilogue slot precompute (R8-proven mapping) ----
    const int o0 = t, o1 = t + 512;
    const bool has1 = (o1 < 768);
    const int c_l0 = o0 >> 4, n_l0 = o0 & 15;
    const int c_l1 = o1 >> 4, n_l1 = o1 & 15;
    const int m0 = c_l0 >> 4, q0 = c_l0 & 3, lr0 = ((c_l0 & 15) >> 2) * 16 + n_l0;
    const int m1 = c_l1 >> 4, q1 = c_l1 & 3, lr1 = ((c_l1 & 15) >> 2) * 16 + n_l1;
    const int c0 = cbase + c_l0, i0n = nbase + n_l0;
    const int c1 = cbase + c_l1, i1n = nbase + n_l1;
    const float im0 = IM[c0 * KPAD + i0n];
    const float im1 = has1 ? IM[c1 * KPAD + i1n] : 0.0f;
    const bool isI0 = (i0n >= N_E), isI1 = (i1n >= N_E);
    float rf0 = 0.0f, rf1 = 0.0f;

    const int ro0 = (cbase + lrow) * KPAD + kw;     // A base (elems) within a buffer

    for (int st = 0; st < NSTEP; ++st){
        const unsigned short* bhp = rh + (size_t)st * RSTEP + ro0;
        const unsigned short* blp = rl + (size_t)st * RSTEP + ro0;

        f32x4 accm[3], accs[3];
        #pragma unroll
        for (int m = 0; m < 3; ++m){
            accm[m] = (f32x4){0.0f, 0.0f, 0.0f, 0.0f};
            accs[m] = (f32x4){0.0f, 0.0f, 0.0f, 0.0f};
        }

        // poll the 2 producer flags covering k-step `pr` (2 lanes active)
        #define POLLP(pr) do {                                                          \
            if (st > 0){                                                                \
                const int wtp = wv * 16 + 2 * (pr) + ln;                                \
                const bool needp = (ln < 2) && (wtp < 125);                             \
                const int wtc = (wtp < 125) ? wtp : 0;                                  \
                const unsigned int* fpp =                                               \
                    flags + ((size_t)st * 256 + (size_t)wtc * 2 + half) * 16;           \
                for (;;){                                                               \
                    unsigned int vv = needp ? __hip_atomic_load(fpp, __ATOMIC_RELAXED,  \
                                               __HIP_MEMORY_SCOPE_AGENT) : 1u;          \
                    if (__all(vv != 0)) break;                                          \
                }                                                                       \
            }                                                                           \
        } while (0)

        bf16x8 fh[3][3], fl[3][3];
        #define LOADF(b, s) do {                                                        \
            fh[b][0] = *reinterpret_cast<const bf16x8*>(bhp + (s) * 32            );    \
            fh[b][1] = *reinterpret_cast<const bf16x8*>(bhp + (s) * 32 + 16 * KPAD);    \
            fh[b][2] = *reinterpret_cast<const bf16x8*>(bhp + (s) * 32 + 32 * KPAD);    \
            fl[b][0] = *reinterpret_cast<const bf16x8*>(blp + (s) * 32            );    \
            fl[b][1] = *reinterpret_cast<const bf16x8*>(blp + (s) * 32 + 16 * KPAD);    \
            fl[b][2] = *reinterpret_cast<const bf16x8*>(blp + (s) * 32 + 32 * KPAD);    \
        } while (0)

        POLLP(0); LOADF(0, 0);
        POLLP(1); LOADF(1, 1);
        #pragma unroll
        for (int s = 0; s < 8; ++s){
            const int cur = s % 3;
            if (s + 2 < 8){
                const int nx = (s + 2) % 3;
                POLLP(s + 2);
                LOADF(nx, s + 2);
            }
            #pragma unroll
            for (int m = 0; m < 3; ++m){
                accm[m] = __builtin_amdgcn_mfma_f32_16x16x32_bf16(fh[cur][m], wh_f[s], accm[m], 0, 0, 0);
                accm[m] = __builtin_amdgcn_mfma_f32_16x16x32_bf16(fh[cur][m], wl_f[s], accm[m], 0, 0, 0);
                accm[m] = __builtin_amdgcn_mfma_f32_16x16x32_bf16(fl[cur][m], wh_f[s], accm[m], 0, 0, 0);
                accs[m] = __builtin_amdgcn_mfma_f32_16x16x32_bf16(fh[cur][m], w2_f[s], accs[m], 0, 0, 0);
                accs[m] = __builtin_amdgcn_mfma_f32_16x16x32_bf16(fl[cur][m], w2_f[s], accs[m], 0, 0, 0);
            }
        }
        #undef LOADF
        #undef POLLP

        // -------- cross-wave K-reduction --------
        #pragma unroll
        for (int m = 0; m < 3; ++m)
            #pragma unroll
            for (int q = 0; q < 4; ++q){
                red[wv][ln][m * 4 + q]      = accm[m][q];
                red[wv][ln][12 + m * 4 + q] = accs[m][q];
            }
        __syncthreads();

        unsigned short* rho = rh + (size_t)(st + 1) * RSTEP;
        unsigned short* rlo = rl + (size_t)(st + 1) * RSTEP;
        const bool track = (st >= NSTEP - NAVG);

        // -------- epilogue: Phi + update + agent r stores --------
        {
            float ms = 0.0f, ss = 0.0f;
            #pragma unroll
            for (int w = 0; w < 8; ++w){
                ms += red[w][lr0][m0 * 4 + q0];
                ss += red[w][lr0][12 + m0 * 4 + q0];
            }
            const float mu = fmaf(0.01f, ms, im0);
            const float sg = sqrtf(fmaf(0.01f, ss, 25.0f));
            const float rate = phi_rate(mu, sg, isI0 ? 0.001f : 0.005f);
            const float dr = (isI0 ? 0.2f : 0.1f) * (rate - rf0);
            const float rnew = rf0 + dr;
            rf0 = rnew;
            const unsigned short hb = bf16_rne(rnew);
            const float hf = __uint_as_float(((unsigned int)hb) << 16);
            __hip_atomic_store(&rho[c0 * KPAD + i0n], hb,
                               __ATOMIC_RELAXED, __HIP_MEMORY_SCOPE_AGENT);
            __hip_atomic_store(&rlo[c0 * KPAD + i0n], bf16_rne(rnew - hf),
                               __ATOMIC_RELAXED, __HIP_MEMORY_SCOPE_AGENT);
            if (track) vbuf[c_l0][n_l0] = fabsf(dr) / fmaxf(fabsf(rnew), 1.0f);
            if (st == NSTEP - 1) out[i0n * NCOND + c0] = rnew;
        }
        if (has1){
            float ms = 0.0f, ss = 0.0f;
            #pragma unroll
            for (int w = 0; w < 8; ++w){
                ms += red[w][lr1][m1 * 4 + q1];
                ss += red[w][lr1][12 + m1 * 4 + q1];
            }
            const float mu = fmaf(0.01f, ms, im1);
            const float sg = sqrtf(fmaf(0.01f, ss, 25.0f));
            const float rate = phi_rate(mu, sg, isI1 ? 0.001f : 0.005f);
            const float dr = (isI1 ? 0.2f : 0.1f) * (rate - rf1);
            const float rnew = rf1 + dr;
            rf1 = rnew;
            const unsigned short hb = bf16_rne(rnew);
            const float hf = __uint_as_float(((unsigned int)hb) << 16);
            __hip_atomic_store(&rho[c1 * KPAD + i1n], hb,
                               __ATOMIC_RELAXED, __HIP_MEMORY_SCOPE_AGENT);
            __hip_atomic_store(&rlo[c1 * KPAD + i1n], bf16_rne(rnew - hf),
                               __ATOMIC_RELAXED, __HIP_MEMORY_SCOPE_AGENT);
            if (track) vbuf[c_l1][n_l1] = fabsf(dr) / fmaxf(fabsf(rnew), 1.0f);
            if (st == NSTEP - 1) out[i1n * NCOND + c1] = rnew;
        }

        // -------- publish: drain r stores, then set flag --------
        vmdrain();
        __syncthreads();        // all waves' stores drained; red[] safe to reuse
        if (st < NSTEP - 1 && t == 0)
            __hip_atomic_store(&flags[((size_t)(st + 1) * 256 + tile * 2 + half) * 16], 1u,
                               __ATOMIC_RELAXED, __HIP_MEMORY_SCOPE_AGENT);
        if (track && t < 48){
            float mx = 0.0f;
            #pragma unroll
            for (int j = 0; j < 16; ++j) mx = fmaxf(mx, vbuf[t][j]);
            mloc[((size_t)(st - (NSTEP - NAVG)) * NBLK + bid) * 48 + t] = mx;
        }
    }
}

// ---------------- finalize A: cross-block max per (step, cond) ----------------
__global__ __launch_bounds__(128) void finalize_max_kernel(
    const float* __restrict__ mloc, float* __restrict__ m2)
{
    int idx = blockIdx.x * 128 + threadIdx.x;   // over 15*96 = 1440
    if (idx >= NAVG * NCOND) return;
    int st = idx / NCOND, c = idx - st * NCOND;
    int half = c / 48, cl = c - half * 48;
    float mx = 0.0f;
    for (int tile = 0; tile < 125; ++tile)
        mx = fmaxf(mx, mloc[((size_t)st * NBLK + tile * 2 + half) * 48 + cl]);
    m2[idx] = mx;
}

// ---------------- finalize B: mean over 15x96, scale by 1/XTOL ----------------
__global__ __launch_bounds__(256) void finalize_sum_kernel(
    const float* __restrict__ m2, float* __restrict__ out)
{
    __shared__ float sbuf[256];
    float s = 0.0f;
    for (int i = threadIdx.x; i < NAVG * NCOND; i += 256) s += m2[i];
    sbuf[threadIdx.x] = s;
    __syncthreads();
    for (int st = 128; st > 0; st >>= 1){
        if (threadIdx.x < st) sbuf[threadIdx.x] += sbuf[threadIdx.x + st];
        __syncthreads();
    }
    if (threadIdx.x == 0)
        out[N_NEUR * NCOND] = sbuf[0] / (float)(NAVG * NCOND) * 1e5f;
}

extern "C" void kernel_launch(void* const* d_in, const int* in_sizes, int n_in,
                              void* d_out, int out_size, void* d_ws, size_t ws_size,
                              hipStream_t stream) {
    const float* jp  = (const float*)d_in[0];
    const float* pp  = (const float*)d_in[1];
    const float* wp  = (const float*)d_in[2];
    const float* rnd = (const float*)d_in[3];
    float* out = (float*)d_out;

    const size_t WELEMS = (size_t)KPAD * KPAD;          // 4,194,304
    const size_t RBUFS  = (size_t)(NSTEP + 1) * RSTEP;  // 61 step-buffers
    unsigned short* Wh  = (unsigned short*)d_ws;
    unsigned short* Wl  = Wh  + WELEMS;
    unsigned short* W2h = Wl  + WELEMS;
    float* IM   = (float*)(W2h + WELEMS);               // 96*2048
    float* mloc = IM + (size_t)NCOND * KPAD;            // 15*250*48 (fully rewritten)
    float* m2   = mloc + (size_t)NAVG * NBLK * 48;      // 1440 (fully rewritten)
    unsigned short* rh = (unsigned short*)(m2 + NAVG * NCOND);
    unsigned short* rl = rh + RBUFS;
    unsigned int* flags = (unsigned int*)(rl + RBUFS);  // 61*256*16 uints

    // zero: step-0 r buffers (r0 = 0, incl. pads) and all flags
    hipMemsetAsync(rh, 0, (size_t)RSTEP * sizeof(unsigned short), stream);
    hipMemsetAsync(rl, 0, (size_t)RSTEP * sizeof(unsigned short), stream);
    hipMemsetAsync(flags, 0, (size_t)(NSTEP + 1) * 256 * 16 * sizeof(unsigned int), stream);

    build_w_kernel<<<(int)(WELEMS / 256), 256, 0, stream>>>(jp, pp, wp, rnd, Wh, Wl, W2h);
    build_im_kernel<<<(int)((NCOND * KPAD) / 256), 256, 0, stream>>>(IM);

    // plain launch: 250 blocks <= 256 CUs, 1 block/CU, no grid-wide sync needed
    solve_kernel<<<dim3(NBLK), dim3(512), 0, stream>>>(
        Wh, Wl, W2h, rh, rl, flags, IM, out, mloc);

    finalize_max_kernel<<<(NAVG * NCOND + 127) / 128, 128, 0, stream>>>(mloc, m2);
    finalize_sum_kernel<<<1, 256, 0, stream>>>(m2, out);
}